// Round 3
// baseline (102.240 us; speedup 1.0000x reference)
//
#include <hip/hip_runtime.h>
#include <stdint.h>

#define BATCH 8192
#define DIM   512
#define NS    16   // 1 positive + 15 negatives

struct OffsetArr { int v[NS]; };

// ---------------------------------------------------------------------------
// Host-side bit-exact replication of:
//   np.random.default_rng(0).choice(np.arange(1, 8192), size=15, replace=False)
// Chain: SeedSequence(0) -> PCG64 (XSL-RR 128/64) -> Generator.choice Floyd
// path (size < pop//50) with 32-bit Lemire bounded draws + final _shuffle_int.
// Only the SET of 15 values matters (softmax denom is permutation-invariant
// and we output only column 0 = offset 0), but we replicate order anyway.
// ---------------------------------------------------------------------------
namespace nprng {

typedef unsigned __int128 u128;

static const uint32_t INIT_A     = 0x43b0d7e5u;
static const uint32_t MULT_A     = 0x931e8875u;
static const uint32_t INIT_B     = 0x8b51f9ddu;
static const uint32_t MULT_B     = 0x58f38dedu;
static const uint32_t MIX_MULT_L = 0xca01f9ddu;
static const uint32_t MIX_MULT_R = 0x4973f715u;

static inline uint32_t hashmix(uint32_t value, uint32_t& hc) {
  value ^= hc;
  hc *= MULT_A;
  value *= hc;
  value ^= value >> 16;
  return value;
}
static inline uint32_t mixfn(uint32_t x, uint32_t y) {
  uint32_t r = x * MIX_MULT_L - y * MIX_MULT_R;
  r ^= r >> 16;
  return r;
}

struct Pcg64 {
  u128 state, inc;
  bool has32;
  uint32_t buf32;
  static inline u128 mult() {
    return ((u128)2549297995355413924ULL << 64) | 4865540595714422341ULL;
  }
  inline void step() { state = state * mult() + inc; }
  void seed(uint64_t s_hi, uint64_t s_lo, uint64_t i_hi, uint64_t i_lo) {
    u128 initstate = ((u128)s_hi << 64) | s_lo;
    u128 initseq   = ((u128)i_hi << 64) | i_lo;
    inc = (initseq << 1) | 1;
    state = 0;
    step();
    state += initstate;
    step();
    has32 = false;
    buf32 = 0;
  }
  inline uint64_t next64() {
    step();  // pcg 128-bit variants: advance, then output NEW state
    uint64_t hi = (uint64_t)(state >> 64);
    uint64_t lo = (uint64_t)state;
    uint32_t rot = (uint32_t)(state >> 122);
    uint64_t v = hi ^ lo;
    return (v >> rot) | (v << ((64u - rot) & 63u));
  }
  inline uint32_t next32() {
    if (has32) { has32 = false; return buf32; }
    uint64_t n = next64();
    has32 = true;
    buf32 = (uint32_t)(n >> 32);   // high half buffered, low half returned
    return (uint32_t)n;
  }
  // numpy buffered_bounded_lemire_uint32: uniform on [0, rng] inclusive
  uint32_t lemire32(uint32_t rng) {
    if (rng == 0) return 0;
    const uint32_t rng_excl = rng + 1;
    uint64_t m = (uint64_t)next32() * (uint64_t)rng_excl;
    uint32_t leftover = (uint32_t)m;
    if (leftover < rng_excl) {
      const uint32_t threshold = (uint32_t)(0u - rng_excl) % rng_excl;
      while (leftover < threshold) {
        m = (uint64_t)next32() * (uint64_t)rng_excl;
        leftover = (uint32_t)m;
      }
    }
    return (uint32_t)(m >> 32);
  }
};

static void compute_offsets(int out[NS]) {
  // ---- SeedSequence(0): pool of 4 u32, entropy = [0] ----
  uint32_t pool[4];
  uint32_t hc = INIT_A;
  pool[0] = hashmix(0u, hc);
  pool[1] = hashmix(0u, hc);
  pool[2] = hashmix(0u, hc);
  pool[3] = hashmix(0u, hc);
  for (int s = 0; s < 4; s++)
    for (int d = 0; d < 4; d++)
      if (s != d) pool[d] = mixfn(pool[d], hashmix(pool[s], hc));
  // ---- generate_state(4, uint64) == 8 u32 words, fresh hash const INIT_B ----
  uint32_t st[8];
  uint32_t hb = INIT_B;
  for (int i = 0; i < 8; i++) {
    uint32_t dv = pool[i & 3];
    dv ^= hb;
    hb *= MULT_B;
    dv *= hb;
    dv ^= dv >> 16;
    st[i] = dv;
  }
  uint64_t w0 = (uint64_t)st[0] | ((uint64_t)st[1] << 32);
  uint64_t w1 = (uint64_t)st[2] | ((uint64_t)st[3] << 32);
  uint64_t w2 = (uint64_t)st[4] | ((uint64_t)st[5] << 32);
  uint64_t w3 = (uint64_t)st[6] | ((uint64_t)st[7] << 32);

  Pcg64 rng;
  // pcg64_set_seed: initstate = (seed[0]<<64)|seed[1], initseq = (inc[0]<<64)|inc[1]
  rng.seed(w0, w1, w2, w3);

  // ---- Generator.choice(arange(1,8192), 15, replace=False): Floyd ----
  const int pop = BATCH - 1;  // 8191
  const int sz  = NS - 1;     // 15
  uint64_t hash_set[32];
  for (int i = 0; i < 32; i++) hash_set[i] = ~0ull;
  const uint64_t mask = 31;   // _gen_mask((uint64)(1.2*15)=18) = 31
  int64_t idx[15];
  for (int j = pop - sz; j < pop; j++) {       // j = 8176..8190
    uint64_t val = rng.lemire32((uint32_t)j);  // uniform [0, j]
    uint64_t loc = val & mask;
    while (hash_set[loc] != ~0ull && hash_set[loc] != val) loc = (loc + 1) & mask;
    if (hash_set[loc] == ~0ull) {
      hash_set[loc] = val;
      idx[j - (pop - sz)] = (int64_t)val;
    } else {  // duplicate -> insert j instead
      loc = (uint64_t)j & mask;
      while (hash_set[loc] != ~0ull) loc = (loc + 1) & mask;
      hash_set[loc] = (uint64_t)j;
      idx[j - (pop - sz)] = (int64_t)j;
    }
  }
  // _shuffle_int(15, first=1)
  for (int i = sz - 1; i >= 1; i--) {
    uint32_t j = rng.lemire32((uint32_t)i);
    int64_t t = idx[j]; idx[j] = idx[i]; idx[i] = t;
  }
  out[0] = 0;
  for (int i = 0; i < sz; i++) out[i + 1] = (int)(idx[i] + 1);  // a = arange(1, B)
}

}  // namespace nprng

// ---------------------------------------------------------------------------
// Device kernel: one wave per batch row. Lane holds 8 q floats; 16 coalesced
// rotated item-row reads; multi-value butterfly reduce (17 shuffles for all
// 16 dots); in-wave softmax over the 16-lane cluster; lane 0 writes prob[0].
// ---------------------------------------------------------------------------
__global__ __launch_bounds__(256) void InBatchNegSampKernel(
    const float* __restrict__ q, const float* __restrict__ items,
    float* __restrict__ out, OffsetArr off) {
  const int lane = threadIdx.x & 63;
  const int wave = threadIdx.x >> 6;
  const int b = (blockIdx.x << 2) | wave;

  const float4* __restrict__ qp =
      reinterpret_cast<const float4*>(q) + (size_t)b * (DIM / 4);
  const float4 q0 = qp[lane];
  const float4 q1 = qp[lane + 64];

  float s[NS];
#pragma unroll
  for (int n = 0; n < NS; n++) {
    const int row = (b + off.v[n]) & (BATCH - 1);
    const float4* __restrict__ ip =
        reinterpret_cast<const float4*>(items) + (size_t)row * (DIM / 4);
    const float4 i0 = ip[lane];
    const float4 i1 = ip[lane + 64];
    float d;
    d = q0.x * i0.x;
    d = fmaf(q0.y, i0.y, d);
    d = fmaf(q0.z, i0.z, d);
    d = fmaf(q0.w, i0.w, d);
    d = fmaf(q1.x, i1.x, d);
    d = fmaf(q1.y, i1.y, d);
    d = fmaf(q1.z, i1.z, d);
    d = fmaf(q1.w, i1.w, d);
    s[n] = d;
  }

  // Butterfly multi-reduce: after 4 stages lane l holds value bitrev4(l&15)
  // summed over its 16-lane group. All indices compile-time (stay in VGPRs).
#define RSTAGE(M, HALF)                                        \
  do {                                                         \
    const bool hi_ = (lane & (M)) != 0;                        \
    _Pragma("unroll")                                          \
    for (int i = 0; i < (HALF); i++) {                         \
      float send_ = hi_ ? s[i] : s[(HALF) + i];                \
      float recv_ = __shfl_xor(send_, (M), 64);                \
      s[i] = (hi_ ? s[(HALF) + i] : s[i]) + recv_;             \
    }                                                          \
  } while (0)
  RSTAGE(1, 8);
  RSTAGE(2, 4);
  RSTAGE(4, 2);
  RSTAGE(8, 1);
#undef RSTAGE

  float v = s[0];
  v += __shfl_xor(v, 16, 64);
  v += __shfl_xor(v, 32, 64);

  // softmax over the 16 values living in each 16-lane cluster
  const float sc = v * 10.0f;  // SCALE=10, TEMP=1
  float mx = sc;
  mx = fmaxf(mx, __shfl_xor(mx, 1, 64));
  mx = fmaxf(mx, __shfl_xor(mx, 2, 64));
  mx = fmaxf(mx, __shfl_xor(mx, 4, 64));
  mx = fmaxf(mx, __shfl_xor(mx, 8, 64));
  const float e = expf(sc - mx);
  float sum = e;
  sum += __shfl_xor(sum, 1, 64);
  sum += __shfl_xor(sum, 2, 64);
  sum += __shfl_xor(sum, 4, 64);
  sum += __shfl_xor(sum, 8, 64);

  if (lane == 0) out[b] = e / sum;  // lane 0 holds n = bitrev4(0) = 0 (positive)
}

extern "C" void kernel_launch(void* const* d_in, const int* in_sizes, int n_in,
                              void* d_out, int out_size, void* d_ws, size_t ws_size,
                              hipStream_t stream) {
  const float* q     = (const float*)d_in[0];
  const float* items = (const float*)d_in[1];
  float* out         = (float*)d_out;

  OffsetArr off;
  nprng::compute_offsets(off.v);  // deterministic, host-only, graph-capture safe

  dim3 grid(BATCH / 4);
  dim3 block(256);
  hipLaunchKernelGGL(InBatchNegSampKernel, grid, block, 0, stream,
                     q, items, out, off);
}